// Round 4
// baseline (46.876 us; speedup 1.0000x reference)
//
#include <hip/hip_runtime.h>
#include <hip/hip_bf16.h>

#define N_CELLS 4096
#define CHUNK 8
#define HID 1024

__global__ __launch_bounds__(256) void cell_mlp_kernel(
    const float* __restrict__ x,
    const float* __restrict__ W1,
    const float* __restrict__ b1,
    const float* __restrict__ W2,
    const float* __restrict__ b2,
    float* __restrict__ out)
{
    const int c = blockIdx.x;      // cell index
    const int t = threadIdx.x;     // 0..255

    // --- broadcast load of this cell's 8-vector input ---
    const float* xc = x + (size_t)c * CHUNK;
    float xv[CHUNK];
#pragma unroll
    for (int k = 0; k < CHUNK; ++k) xv[k] = xc[k];

    // --- layer 1: thread t computes hidden units 4t..4t+3 ---
    // W1 layout: [cell][k=0..7][h=0..1023] -> float4 at (k*HID + 4t) is coalesced
    const float* W1c = W1 + (size_t)c * CHUNK * HID;
    const float* b1c = b1 + (size_t)c * HID;

    float4 bb = *reinterpret_cast<const float4*>(b1c + 4 * t);
    float acc0 = bb.x, acc1 = bb.y, acc2 = bb.z, acc3 = bb.w;

#pragma unroll
    for (int k = 0; k < CHUNK; ++k) {
        float4 w = *reinterpret_cast<const float4*>(W1c + k * HID + 4 * t);
        acc0 += xv[k] * w.x;
        acc1 += xv[k] * w.y;
        acc2 += xv[k] * w.z;
        acc3 += xv[k] * w.w;
    }

    float h0 = tanhf(acc0);
    float h1 = tanhf(acc1);
    float h2 = tanhf(acc2);
    float h3 = tanhf(acc3);

    // --- layer 2: accumulate partial y[8] ---
    // W2 layout: [cell][h=0..1023][j=0..7] -> thread reads 128 contiguous bytes
    const float* W2c = W2 + (size_t)c * HID * CHUNK;
    float y[CHUNK];
#pragma unroll
    for (int j = 0; j < CHUNK; ++j) y[j] = 0.0f;

    const float hv[4] = {h0, h1, h2, h3};
#pragma unroll
    for (int i = 0; i < 4; ++i) {
        const float* wrow = W2c + (size_t)(4 * t + i) * CHUNK;
        float4 a = *reinterpret_cast<const float4*>(wrow);
        float4 b = *reinterpret_cast<const float4*>(wrow + 4);
        y[0] += hv[i] * a.x;
        y[1] += hv[i] * a.y;
        y[2] += hv[i] * a.z;
        y[3] += hv[i] * a.w;
        y[4] += hv[i] * b.x;
        y[5] += hv[i] * b.y;
        y[6] += hv[i] * b.z;
        y[7] += hv[i] * b.w;
    }

    // --- reduce across the 64-lane wave ---
#pragma unroll
    for (int j = 0; j < CHUNK; ++j) {
#pragma unroll
        for (int off = 32; off > 0; off >>= 1) {
            y[j] += __shfl_down(y[j], off, 64);
        }
    }

    // --- cross-wave reduce via LDS (4 waves per block) ---
    __shared__ float red[4][CHUNK];
    const int wave = t >> 6;
    const int lane = t & 63;
    if (lane == 0) {
#pragma unroll
        for (int j = 0; j < CHUNK; ++j) red[wave][j] = y[j];
    }
    __syncthreads();

    if (t < CHUNK) {
        float s = red[0][t] + red[1][t] + red[2][t] + red[3][t]
                + b2[(size_t)c * CHUNK + t];
        out[(size_t)c * CHUNK + t] = s;
    }
}

extern "C" void kernel_launch(void* const* d_in, const int* in_sizes, int n_in,
                              void* d_out, int out_size, void* d_ws, size_t ws_size,
                              hipStream_t stream) {
    const float* x  = (const float*)d_in[0];
    const float* W1 = (const float*)d_in[1];
    const float* b1 = (const float*)d_in[2];
    const float* W2 = (const float*)d_in[3];
    const float* b2 = (const float*)d_in[4];
    float* out = (float*)d_out;

    cell_mlp_kernel<<<N_CELLS, 256, 0, stream>>>(x, W1, b1, W2, b2, out);
}

// Round 7
// 46.359 us; speedup vs baseline: 1.0111x; 1.0111x over previous
//
#include <hip/hip_runtime.h>
#include <hip/hip_bf16.h>

#define N_CELLS 4096
#define CHUNK 8
#define HID 1024

__global__ __launch_bounds__(256) void cell_mlp_kernel(
    const float* __restrict__ x,
    const float* __restrict__ W1,
    const float* __restrict__ b1,
    const float* __restrict__ W2,
    const float* __restrict__ b2,
    float* __restrict__ out)
{
    const int c = blockIdx.x;      // cell index
    const int t = threadIdx.x;     // 0..255

    // ---- issue ALL loads up front, FIFO-ordered so the first compute wait
    //      (vmcnt) leaves the W2 batch still in flight ----

    // x broadcast: 2 x float4 (same line for all threads -> L1 broadcast)
    const float* xc = x + (size_t)c * CHUNK;
    float4 xlo = *reinterpret_cast<const float4*>(xc);
    float4 xhi = *reinterpret_cast<const float4*>(xc + 4);

    // bias for hidden units 4t..4t+3
    float4 bb = *reinterpret_cast<const float4*>(b1 + (size_t)c * HID + 4 * t);

    // W1: [cell][k=0..7][h] -> float4 at (k*HID + 4t), coalesced across lanes
    const float* W1c = W1 + (size_t)c * CHUNK * HID + 4 * t;
    float4 w1r[CHUNK];
#pragma unroll
    for (int k = 0; k < CHUNK; ++k)
        w1r[k] = *reinterpret_cast<const float4*>(W1c + k * HID);

    // W2: [cell][h][j=0..7] -> thread owns rows 4t..4t+3 = 128 contiguous B
    const float* W2c = W2 + (size_t)c * HID * CHUNK + (size_t)(4 * t) * CHUNK;
    float4 w2r[CHUNK];
#pragma unroll
    for (int i = 0; i < CHUNK; ++i)
        w2r[i] = *reinterpret_cast<const float4*>(W2c + 4 * i);

    // pin the load issue order: nothing crosses this point
    __builtin_amdgcn_sched_barrier(0);

    // ---- layer 1: waits only for x/bb/W1 (vmcnt leaves W2 outstanding) ----
    const float xv[CHUNK] = {xlo.x, xlo.y, xlo.z, xlo.w,
                             xhi.x, xhi.y, xhi.z, xhi.w};
    float acc0 = bb.x, acc1 = bb.y, acc2 = bb.z, acc3 = bb.w;
#pragma unroll
    for (int k = 0; k < CHUNK; ++k) {
        acc0 += xv[k] * w1r[k].x;
        acc1 += xv[k] * w1r[k].y;
        acc2 += xv[k] * w1r[k].z;
        acc3 += xv[k] * w1r[k].w;
    }

    const float hv[4] = {tanhf(acc0), tanhf(acc1), tanhf(acc2), tanhf(acc3)};

    // ---- layer 2: W2 latency was hidden under layer-1 FMA + tanh ----
    float y[CHUNK];
#pragma unroll
    for (int j = 0; j < CHUNK; ++j) y[j] = 0.0f;

#pragma unroll
    for (int i = 0; i < 4; ++i) {
        const float4 a = w2r[2 * i];
        const float4 b = w2r[2 * i + 1];
        y[0] += hv[i] * a.x;
        y[1] += hv[i] * a.y;
        y[2] += hv[i] * a.z;
        y[3] += hv[i] * a.w;
        y[4] += hv[i] * b.x;
        y[5] += hv[i] * b.y;
        y[6] += hv[i] * b.z;
        y[7] += hv[i] * b.w;
    }

    // ---- reduce across the 64-lane wave ----
#pragma unroll
    for (int j = 0; j < CHUNK; ++j) {
#pragma unroll
        for (int off = 32; off > 0; off >>= 1) {
            y[j] += __shfl_down(y[j], off, 64);
        }
    }

    // ---- cross-wave reduce via LDS (4 waves per block) ----
    __shared__ float red[4][CHUNK];
    const int wave = t >> 6;
    const int lane = t & 63;
    if (lane == 0) {
#pragma unroll
        for (int j = 0; j < CHUNK; ++j) red[wave][j] = y[j];
    }
    __syncthreads();

    if (t < CHUNK) {
        float s = red[0][t] + red[1][t] + red[2][t] + red[3][t]
                + b2[(size_t)c * CHUNK + t];
        out[(size_t)c * CHUNK + t] = s;
    }
}

extern "C" void kernel_launch(void* const* d_in, const int* in_sizes, int n_in,
                              void* d_out, int out_size, void* d_ws, size_t ws_size,
                              hipStream_t stream) {
    const float* x  = (const float*)d_in[0];
    const float* W1 = (const float*)d_in[1];
    const float* b1 = (const float*)d_in[2];
    const float* W2 = (const float*)d_in[3];
    const float* b2 = (const float*)d_in[4];
    float* out = (float*)d_out;

    cell_mlp_kernel<<<N_CELLS, 256, 0, stream>>>(x, W1, b1, W2, b2, out);
}